// Round 6
// baseline (47.032 us; speedup 1.0000x reference)
//
#include <hip/hip_runtime.h>
#include <math.h>

#define B_  16
#define T_  16
#define N_  256
#define D_  384
#define Q_  384
#define K_  16
#define BT_ (B_ * T_)

// 3 kernels, d_ws as scratch (R2/R4 comparison proved the ws poison-fill is
// NOT in the timed path; earlier regressions were small-grid latency kernels).
// ws layout: qp [BT_*D_ f32] | sc [BT_*N_ f32]

// ---------------------------------------------------------------------------
// K1: qp[bt] = queries[bt] @ W_in + b_in.  256 blocks x 768 thr, 2-way split-K.
// ---------------------------------------------------------------------------
__global__ __launch_bounds__(768)
void qproj_kernel(const float* __restrict__ queries,  // [BT_, Q_]
                  const float* __restrict__ W_in,     // [Q_, D_]
                  const float* __restrict__ b_in,     // [D_]
                  float* __restrict__ qp)             // [BT_, D_]
{
    const int bt  = blockIdx.x;
    const int tid = threadIdx.x;            // 0..767

    __shared__ float s_q[Q_];
    __shared__ float s_part[2 * D_];

    if (tid < Q_) s_q[tid] = queries[(size_t)bt * Q_ + tid];
    __syncthreads();

    {
        const int half = tid >= D_;
        const int d    = tid - half * D_;
        const int q0   = half * (Q_ / 2);
        float acc = 0.f;
        #pragma unroll 8
        for (int q = q0; q < q0 + Q_ / 2; ++q)
            acc += s_q[q] * W_in[(size_t)q * D_ + d];
        s_part[tid] = acc;
    }
    __syncthreads();
    if (tid < D_)
        qp[(size_t)bt * D_ + tid] = s_part[tid] + s_part[tid + D_] + b_in[tid];
}

// ---------------------------------------------------------------------------
// K2: scores[bt, n] = dot(qp[bt], patch[bt, n, :]).
// grid (2, BT_) = 512 blocks x 1024 thr; block (h, bt) does rows h*128..+128.
// 64 groups of 16 lanes, 2 rows per group; float4 loads; pure stream.
// ---------------------------------------------------------------------------
__global__ __launch_bounds__(1024)
void scores_kernel(const float* __restrict__ patch,   // [BT_, N_, D_]
                   const float* __restrict__ qp,      // [BT_, D_]
                   float* __restrict__ sc)            // [BT_, N_]
{
    const int h    = blockIdx.x;          // 0..1
    const int bt   = blockIdx.y;
    const int tid  = threadIdx.x;         // 0..1023
    const int grp  = tid >> 4;            // 0..63
    const int sl   = tid & 15;

    __shared__ float s_qp[D_];
    if (tid < D_) s_qp[tid] = qp[(size_t)bt * D_ + tid];
    __syncthreads();

    const float4* s_qp4 = reinterpret_cast<const float4*>(s_qp);
    const float* __restrict__ ptile = patch + (size_t)bt * N_ * D_;

    #pragma unroll
    for (int it = 0; it < 2; ++it) {
        const int n = h * 128 + it * 64 + grp;
        const float* prow = ptile + (size_t)n * D_;
        float p = 0.f;
        #pragma unroll
        for (int c = 0; c < 6; ++c) {
            const float4 a = *reinterpret_cast<const float4*>(prow + c * 64 + 4 * sl);
            const float4 b = s_qp4[c * 16 + sl];
            p += a.x * b.x + a.y * b.y + a.z * b.z + a.w * b.w;
        }
        #pragma unroll
        for (int off = 8; off; off >>= 1)
            p += __shfl_xor(p, off, 16);
        if (sl == 0) sc[(size_t)bt * N_ + n] = p;   // TEMP == 1
    }
}

// ---------------------------------------------------------------------------
// K3: softmax + exact top-K + weighted sum + out-proj.  256 blocks x 1024 thr.
// ---------------------------------------------------------------------------
__global__ __launch_bounds__(1024)
void finish_kernel(const float* __restrict__ patch,   // [BT_, N_, D_]
                   const float* __restrict__ sc,      // [BT_, N_]
                   const float* __restrict__ W_out,   // [D_, Q_]
                   const float* __restrict__ b_out,   // [Q_]
                   float* __restrict__ out)           // [BT_, Q_]
{
    const int bt   = blockIdx.x;
    const int tid  = threadIdx.x;       // 0..1023
    const int lane = tid & 63;
    const int wave = tid >> 6;          // 0..15

    __shared__ float s_sc[N_];
    __shared__ int   s_cnt4[N_][4];
    __shared__ float s_red[4];
    __shared__ float s_red2[4][2];
    __shared__ float s_w[K_];
    __shared__ int   s_ix[K_];
    __shared__ float s_part[2 * D_];
    __shared__ float s_od[D_];

    const float* __restrict__ ptile = patch + (size_t)bt * N_ * D_;

    if (tid < N_) s_sc[tid] = sc[(size_t)bt * N_ + tid];
    __syncthreads();

    // block max (waves 0-3)
    if (tid < N_) {
        float v = s_sc[tid];
        #pragma unroll
        for (int off = 32; off; off >>= 1) v = fmaxf(v, __shfl_xor(v, off));
        if (lane == 0) s_red[wave] = v;
    }
    // rank partial counts (all 1024 threads; 64 comparisons each)
    {
        const int i   = tid >> 2;       // 0..255
        const int sub = tid & 3;        // j in [sub*64, sub*64+64)
        const float si = s_sc[i];
        int c = 0;
        #pragma unroll 8
        for (int j = sub * 64; j < sub * 64 + 64; ++j) {
            const float sj = s_sc[j];
            c += (int)(sj > si) | ((int)(sj == si) & (int)(j < i));
        }
        s_cnt4[i][sub] = c;
    }
    __syncthreads();

    // e, Z, SK (threads < 256)
    float e = 0.f;
    int   cnt = N_;
    if (tid < N_) {
        const float mx = fmaxf(fmaxf(s_red[0], s_red[1]), fmaxf(s_red[2], s_red[3]));
        cnt = s_cnt4[tid][0] + s_cnt4[tid][1] + s_cnt4[tid][2] + s_cnt4[tid][3];
        e = __expf(s_sc[tid] - mx);

        float z  = e;
        float sk = (cnt < K_) ? e : 0.f;
        #pragma unroll
        for (int off = 32; off; off >>= 1) {
            z  += __shfl_xor(z, off);
            sk += __shfl_xor(sk, off);
        }
        if (lane == 0) { s_red2[wave][0] = z; s_red2[wave][1] = sk; }
    }
    __syncthreads();

    // weight_i = e_i / (SK + EPS*Z)
    {
        const float Z  = s_red2[0][0] + s_red2[1][0] + s_red2[2][0] + s_red2[3][0];
        const float SK = s_red2[0][1] + s_red2[1][1] + s_red2[2][1] + s_red2[3][1];
        const float inv = 1.f / (SK + 1e-8f * Z);
        if (tid < N_ && cnt < K_) {
            s_ix[cnt] = tid;
            s_w[cnt]  = e * inv;
        }
    }
    __syncthreads();

    // weighted sum over K rows (L2/L3-hot): 768 thr, 2-way split over j
    if (tid < 2 * D_) {
        const int half = tid >= D_;
        const int d    = tid - half * D_;
        const int j0   = half * (K_ / 2);
        float acc = 0.f;
        #pragma unroll
        for (int j = j0; j < j0 + K_ / 2; ++j)
            acc += s_w[j] * ptile[(size_t)s_ix[j] * D_ + d];
        s_part[tid] = acc;
    }
    __syncthreads();
    if (tid < D_) s_od[tid] = s_part[tid] + s_part[tid + D_];
    __syncthreads();

    // out-proj: 768 thr, 2-way split-K over d
    if (tid < 2 * Q_) {
        const int half = tid >= Q_;
        const int q    = tid - half * Q_;
        const int d0   = half * (D_ / 2);
        float acc = 0.f;
        #pragma unroll 8
        for (int d = d0; d < d0 + D_ / 2; ++d)
            acc += s_od[d] * W_out[(size_t)d * Q_ + q];
        s_part[tid] = acc;
    }
    __syncthreads();
    if (tid < Q_)
        out[(size_t)bt * Q_ + tid] = s_part[tid] + s_part[tid + Q_] + b_out[tid];
}

extern "C" void kernel_launch(void* const* d_in, const int* in_sizes, int n_in,
                              void* d_out, int out_size, void* d_ws, size_t ws_size,
                              hipStream_t stream) {
    const float* queries = (const float*)d_in[0];
    const float* patch   = (const float*)d_in[1];
    const float* W_in    = (const float*)d_in[2];
    const float* b_in    = (const float*)d_in[3];
    const float* W_out   = (const float*)d_in[4];
    const float* b_out   = (const float*)d_in[5];
    float* out = (float*)d_out;

    float* qp = (float*)d_ws;                 // [BT_, D_]
    float* sc = qp + (size_t)BT_ * D_;        // [BT_, N_]

    qproj_kernel<<<dim3(BT_), dim3(768), 0, stream>>>(queries, W_in, b_in, qp);
    scores_kernel<<<dim3(2, BT_), dim3(1024), 0, stream>>>(patch, qp, sc);
    finish_kernel<<<dim3(BT_), dim3(1024), 0, stream>>>(patch, sc, W_out, b_out, out);
}

// Round 7
// 37.858 us; speedup vs baseline: 1.2423x; 1.2423x over previous
//
#include <hip/hip_runtime.h>
#include <math.h>

#define B_  16
#define T_  16
#define N_  256
#define D_  384
#define Q_  384
#define K_  16
#define BT_ (B_ * T_)

// 2 graph nodes (R6 showed each extra node ~+2us). d_ws holds qp.
// R7 change: hand software-pipelining for ILP — the R5 kernels compiled to
// VGPR=32 with only 6 loads in flight (latency-bound, not BW-bound).

// ---------------------------------------------------------------------------
// K1: qp[bt] = queries[bt] @ W_in + b_in.  256 blocks x 768 thr.
// 2-way split-K, 4 independent accumulator chains (>=16 L2 loads in flight).
// ---------------------------------------------------------------------------
__global__ __launch_bounds__(768)
void qproj_kernel(const float* __restrict__ queries,  // [BT_, Q_]
                  const float* __restrict__ W_in,     // [Q_, D_]
                  const float* __restrict__ b_in,     // [D_]
                  float* __restrict__ qp)             // [BT_, D_]
{
    const int bt  = blockIdx.x;
    const int tid = threadIdx.x;            // 0..767

    __shared__ __align__(16) float s_q[Q_];
    __shared__ float s_part[2 * D_];

    if (tid < Q_) s_q[tid] = queries[(size_t)bt * Q_ + tid];
    __syncthreads();

    {
        const int half = tid >= D_;
        const int d    = tid - half * D_;
        const int q0   = half * (Q_ / 2);
        float a0 = 0.f, a1 = 0.f, a2 = 0.f, a3 = 0.f;
        #pragma unroll 4
        for (int q = q0; q < q0 + Q_ / 2; q += 4) {
            a0 += s_q[q]     * W_in[(size_t)(q)     * D_ + d];
            a1 += s_q[q + 1] * W_in[(size_t)(q + 1) * D_ + d];
            a2 += s_q[q + 2] * W_in[(size_t)(q + 2) * D_ + d];
            a3 += s_q[q + 3] * W_in[(size_t)(q + 3) * D_ + d];
        }
        s_part[tid] = (a0 + a1) + (a2 + a3);
    }
    __syncthreads();
    if (tid < D_)
        qp[(size_t)bt * D_ + tid] = s_part[tid] + s_part[tid + D_] + b_in[tid];
}

// ---------------------------------------------------------------------------
// K2: per (b,t): scores -> softmax -> exact top-K -> weighted sum -> outproj.
// 256 blocks x 1024 threads. Scores phase: qp hoisted to regs, 2-row
// double-buffered patch loads (12-18 float4 in flight).
// ---------------------------------------------------------------------------
__global__ __launch_bounds__(1024, 4)
void fused_kernel(const float* __restrict__ patch,   // [BT_, N_, D_]
                  const float* __restrict__ qp,      // [BT_, D_]
                  const float* __restrict__ W_out,   // [D_, Q_]
                  const float* __restrict__ b_out,   // [Q_]
                  float* __restrict__ out)           // [BT_, Q_]
{
    const int bt   = blockIdx.x;
    const int tid  = threadIdx.x;       // 0..1023
    const int lane = tid & 63;
    const int wave = tid >> 6;          // 0..15

    __shared__ __align__(16) float s_qp[D_];
    __shared__ float s_sc[N_];
    __shared__ int   s_cnt4[N_][4];
    __shared__ float s_red[4];
    __shared__ float s_red2[4][2];
    __shared__ float s_w[K_];
    __shared__ int   s_ix[K_];
    __shared__ float s_part[2 * D_];
    __shared__ float s_od[D_];

    const float* __restrict__ ptile = patch + (size_t)bt * N_ * D_;

    if (tid < D_) s_qp[tid] = qp[(size_t)bt * D_ + tid];
    __syncthreads();

    // ---- scores: 64 groups of 16 lanes; each group 4 rows; double-buffered --
    {
        const int g  = lane >> 4;       // 0..3
        const int sl = lane & 15;
        const int n0 = wave * 4 + g;    // rows n0 + {0,64,128,192}
        const float4* s_qp4 = reinterpret_cast<const float4*>(s_qp);

        float4 qv[6];
        #pragma unroll
        for (int c = 0; c < 6; ++c) qv[c] = s_qp4[c * 16 + sl];

        float4 A[6], Bu[6];

#define LOADROW(dst, it) {                                                     \
        const float* pr = ptile + (size_t)(n0 + (it) * 64) * D_;               \
        _Pragma("unroll")                                                      \
        for (int c = 0; c < 6; ++c)                                            \
            dst[c] = *reinterpret_cast<const float4*>(pr + c * 64 + 4 * sl); }

#define DOTSTORE(src, it) {                                                    \
        float p = 0.f;                                                         \
        _Pragma("unroll")                                                      \
        for (int c = 0; c < 6; ++c)                                            \
            p += src[c].x * qv[c].x + src[c].y * qv[c].y                       \
               + src[c].z * qv[c].z + src[c].w * qv[c].w;                      \
        _Pragma("unroll")                                                      \
        for (int off = 8; off; off >>= 1) p += __shfl_xor(p, off, 16);         \
        if (sl == 0) s_sc[n0 + (it) * 64] = p; }

        LOADROW(A, 0)
        LOADROW(Bu, 1)
        DOTSTORE(A, 0)
        LOADROW(A, 2)
        DOTSTORE(Bu, 1)
        LOADROW(Bu, 3)
        DOTSTORE(A, 2)
        DOTSTORE(Bu, 3)
#undef LOADROW
#undef DOTSTORE
    }
    __syncthreads();

    // ---- block max (waves 0-3) + rank partial counts (all 1024 threads) ----
    if (tid < N_) {
        float v = s_sc[tid];
        #pragma unroll
        for (int off = 32; off; off >>= 1) v = fmaxf(v, __shfl_xor(v, off));
        if (lane == 0) s_red[wave] = v;
    }
    {
        const int i   = tid >> 2;       // 0..255
        const int sub = tid & 3;        // j in [sub*64, sub*64+64)
        const float si = s_sc[i];
        int c = 0;
        #pragma unroll 8
        for (int j = sub * 64; j < sub * 64 + 64; ++j) {
            const float sj = s_sc[j];
            c += (int)(sj > si) | ((int)(sj == si) & (int)(j < i));
        }
        s_cnt4[i][sub] = c;
    }
    __syncthreads();

    // ---- e, Z, SK (threads < 256) ----
    float e = 0.f;
    int   cnt = N_;
    if (tid < N_) {
        const float mx = fmaxf(fmaxf(s_red[0], s_red[1]), fmaxf(s_red[2], s_red[3]));
        cnt = s_cnt4[tid][0] + s_cnt4[tid][1] + s_cnt4[tid][2] + s_cnt4[tid][3];
        e = __expf(s_sc[tid] - mx);

        float z  = e;
        float sk = (cnt < K_) ? e : 0.f;
        #pragma unroll
        for (int off = 32; off; off >>= 1) {
            z  += __shfl_xor(z, off);
            sk += __shfl_xor(sk, off);
        }
        if (lane == 0) { s_red2[wave][0] = z; s_red2[wave][1] = sk; }
    }
    __syncthreads();

    // weight_i = softmax_i / (sum_topk + EPS) = e_i / (SK + EPS*Z)
    {
        const float Z  = s_red2[0][0] + s_red2[1][0] + s_red2[2][0] + s_red2[3][0];
        const float SK = s_red2[0][1] + s_red2[1][1] + s_red2[2][1] + s_red2[3][1];
        const float inv = 1.f / (SK + 1e-8f * Z);
        if (tid < N_ && cnt < K_) {
            s_ix[cnt] = tid;
            s_w[cnt]  = e * inv;
        }
    }
    __syncthreads();

    // ---- weighted sum over K rows: 768 thr, 2-way split over j ----
    if (tid < 2 * D_) {
        const int half = tid >= D_;
        const int d    = tid - half * D_;
        const int j0   = half * (K_ / 2);
        float acc = 0.f;
        #pragma unroll
        for (int j = j0; j < j0 + K_ / 2; ++j)
            acc += s_w[j] * ptile[(size_t)s_ix[j] * D_ + d];
        s_part[tid] = acc;
    }
    __syncthreads();
    if (tid < D_) s_od[tid] = s_part[tid] + s_part[tid + D_];
    __syncthreads();

    // ---- out-proj: 768 thr, 2-way split-K, 4 accumulator chains ----
    if (tid < 2 * Q_) {
        const int half = tid >= Q_;
        const int q    = tid - half * Q_;
        const int d0   = half * (D_ / 2);
        float a0 = 0.f, a1 = 0.f, a2 = 0.f, a3 = 0.f;
        #pragma unroll 4
        for (int d = d0; d < d0 + D_ / 2; d += 4) {
            a0 += s_od[d]     * W_out[(size_t)(d)     * Q_ + q];
            a1 += s_od[d + 1] * W_out[(size_t)(d + 1) * Q_ + q];
            a2 += s_od[d + 2] * W_out[(size_t)(d + 2) * Q_ + q];
            a3 += s_od[d + 3] * W_out[(size_t)(d + 3) * Q_ + q];
        }
        s_part[tid] = (a0 + a1) + (a2 + a3);
    }
    __syncthreads();
    if (tid < Q_)
        out[(size_t)bt * Q_ + tid] = s_part[tid] + s_part[tid + Q_] + b_out[tid];
}

extern "C" void kernel_launch(void* const* d_in, const int* in_sizes, int n_in,
                              void* d_out, int out_size, void* d_ws, size_t ws_size,
                              hipStream_t stream) {
    const float* queries = (const float*)d_in[0];
    const float* patch   = (const float*)d_in[1];
    const float* W_in    = (const float*)d_in[2];
    const float* b_in    = (const float*)d_in[3];
    const float* W_out   = (const float*)d_in[4];
    const float* b_out   = (const float*)d_in[5];
    float* out = (float*)d_out;

    float* qp = (float*)d_ws;                 // [BT_, D_]

    qproj_kernel<<<dim3(BT_), dim3(768), 0, stream>>>(queries, W_in, b_in, qp);
    fused_kernel<<<dim3(BT_), dim3(1024), 0, stream>>>(patch, qp, W_out, b_out, out);
}